// Round 10
// baseline (277.872 us; speedup 1.0000x reference)
//
#include <hip/hip_runtime.h>

#define N_NODES 100000
#define N_EDGES 3200000
#define N_QUADS (N_EDGES / 4)            // 800000

// ---- hist geometry: P=4 partitions, 64 slices, 256 blocks, 1 block/CU ----
// XCD-locality: p = bid>>6, slice = bid&63 -> same-slice blocks {s,s+64,s+128,s+192}
// all land on the same XCD (64%8==0), slice data L2-resident after first touch.
// Branch-free routing: hist has 64 per-lane trash slots at [PART, PART+64);
// out-of-partition edges add there via one v_cndmask -> every ds_add issues
// dense (all 64 lanes), P x fewer LDS-atomic instructions than predicated form.
#define P_PARTS  4
#define PART     25600                   // 4*25600 = 102400 >= N
#define HSZ      (PART + 64)             // +64 trash slots; 102.7 KB LDS
#define SLICES   64
#define SLICE_Q  (N_QUADS / SLICES)      // 12500 quads per slice (exact)
#define BLOCKS_H (P_PARTS * SLICES)      // 256
#define T_HIST   1024

// ---------------- workspace layout (bytes) ----------------
#define OFF_STATS 0                      // double[5] (zeroed)
#define OFF_DEG   1024                   // float[102400] (zeroed)
#define OFF_ACC   410624                 // float[102400] (encoder writes [0,N))
#define OFF_DINV  820224                 // float[N]
#define OFF_GS    1220224                // float[N]
// total ~1.62 MB

// per-wave int64-vs-int32 detection: high words of first 64 int64 slots
__device__ __forceinline__ bool detect_is64(const void* ei) {
    const int* p = (const int*)ei;
    int lane = threadIdx.x & 63;
    int hi = p[2 * lane + 1];
    unsigned long long m = __ballot(hi != 0);
    return m == 0ull;  // wave-uniform
}

// ---- K1: degree histogram straight from int64 dst + BN stats ----
__global__ __launch_bounds__(T_HIST) void stats_deg_kernel(
        const float* __restrict__ x, const void* __restrict__ ei,
        double* __restrict__ stats, float* __restrict__ degf) {
    __shared__ float hist[HSZ];
    bool is64 = detect_is64(ei);
    const int tid = threadIdx.x;
    const int p = blockIdx.x >> 6;       // XCD-locality mapping
    const int slice = blockIdx.x & 63;
    const int base = p * PART;
    const unsigned trash = PART + (unsigned)(tid & 63);

    for (int i = tid; i < HSZ; i += T_HIST) hist[i] = 0.f;
    __syncthreads();

    int q0 = slice * SLICE_Q, q1 = q0 + SLICE_Q;
#define DGE(va, vb) { \
        unsigned l0 = (unsigned)((int)(va).x - base); \
        unsigned l1 = (unsigned)((int)(va).y - base); \
        unsigned l2 = (unsigned)((int)(vb).x - base); \
        unsigned l3 = (unsigned)((int)(vb).y - base); \
        atomicAdd(&hist[l0 < PART ? l0 : trash], 1.0f); \
        atomicAdd(&hist[l1 < PART ? l1 : trash], 1.0f); \
        atomicAdd(&hist[l2 < PART ? l2 : trash], 1.0f); \
        atomicAdd(&hist[l3 < PART ? l3 : trash], 1.0f); }
    if (is64) {
        const longlong2* dq = (const longlong2*)((const long long*)ei + N_EDGES);
        int qb = q0;
        for (; qb + 4 * T_HIST <= q1; qb += 4 * T_HIST) {
            longlong2 a0 = dq[2 * (qb + tid)],              a1 = dq[2 * (qb + tid) + 1];
            longlong2 b0 = dq[2 * (qb + T_HIST + tid)],     b1 = dq[2 * (qb + T_HIST + tid) + 1];
            longlong2 c0 = dq[2 * (qb + 2 * T_HIST + tid)], c1 = dq[2 * (qb + 2 * T_HIST + tid) + 1];
            longlong2 d0 = dq[2 * (qb + 3 * T_HIST + tid)], d1 = dq[2 * (qb + 3 * T_HIST + tid) + 1];
            DGE(a0, a1) DGE(b0, b1) DGE(c0, c1) DGE(d0, d1)
        }
        for (int q = qb + tid; q < q1; q += T_HIST) {
            longlong2 a0 = dq[2 * q], a1 = dq[2 * q + 1];
            DGE(a0, a1)
        }
    } else {
        const int4* dq = (const int4*)((const int*)ei + N_EDGES);
        int qb = q0;
#define DG4(V) { \
        unsigned l0 = (unsigned)((V).x - base); \
        unsigned l1 = (unsigned)((V).y - base); \
        unsigned l2 = (unsigned)((V).z - base); \
        unsigned l3 = (unsigned)((V).w - base); \
        atomicAdd(&hist[l0 < PART ? l0 : trash], 1.0f); \
        atomicAdd(&hist[l1 < PART ? l1 : trash], 1.0f); \
        atomicAdd(&hist[l2 < PART ? l2 : trash], 1.0f); \
        atomicAdd(&hist[l3 < PART ? l3 : trash], 1.0f); }
        for (; qb + 4 * T_HIST <= q1; qb += 4 * T_HIST) {
            int4 a = dq[qb + tid];
            int4 b = dq[qb + T_HIST + tid];
            int4 c = dq[qb + 2 * T_HIST + tid];
            int4 d = dq[qb + 3 * T_HIST + tid];
            DG4(a) DG4(b) DG4(c) DG4(d)
        }
        for (int q = qb + tid; q < q1; q += T_HIST) { int4 a = dq[q]; DG4(a) }
#undef DG4
    }
#undef DGE
    __syncthreads();
    // flush [0,PART) only (trash not flushed); consecutive addrs coalesce
    for (int i = tid; i < PART; i += T_HIST) {
        float v = hist[i];
        if (v != 0.f) unsafeAtomicAdd(&degf[base + i], v);
    }

    // ---- BN stats over x (blocks covering node range only; block-uniform guard) ----
    if (blockIdx.x * T_HIST < N_NODES) {
        __shared__ double sh[5][T_HIST / 64];
        int n = blockIdx.x * T_HIST + tid;
        double a0 = 0, a1 = 0, a2 = 0, a3 = 0, a4 = 0;
        if (n < N_NODES) {
            float2 v = ((const float2*)x)[n];
            double x0 = v.x, x1 = v.y;
            a0 = x0; a1 = x1; a2 = x0 * x0; a3 = x1 * x1; a4 = x0 * x1;
        }
        for (int off = 32; off; off >>= 1) {
            a0 += __shfl_down(a0, off);
            a1 += __shfl_down(a1, off);
            a2 += __shfl_down(a2, off);
            a3 += __shfl_down(a3, off);
            a4 += __shfl_down(a4, off);
        }
        int w = tid >> 6;
        if ((tid & 63) == 0) {
            sh[0][w] = a0; sh[1][w] = a1; sh[2][w] = a2; sh[3][w] = a3; sh[4][w] = a4;
        }
        __syncthreads();
        if (tid == 0) {
            double t0 = 0, t1 = 0, t2 = 0, t3 = 0, t4 = 0;
            for (int i = 0; i < T_HIST / 64; i++) {
                t0 += sh[0][i]; t1 += sh[1][i]; t2 += sh[2][i]; t3 += sh[3][i]; t4 += sh[4][i];
            }
            atomicAdd(&stats[0], t0);
            atomicAdd(&stats[1], t1);
            atomicAdd(&stats[2], t2);
            atomicAdd(&stats[3], t3);
            atomicAdd(&stats[4], t4);
        }
    }
}

// ---- K2: encoder: gs[n] = dinv * (GB + sum_c PReLU(Ax0+Bx1+C) U[c]) ----
__global__ void encoder_kernel(const float* __restrict__ x,
                               const double* __restrict__ stats,
                               const float* __restrict__ w1, const float* __restrict__ b1,
                               const float* __restrict__ gamma, const float* __restrict__ beta,
                               const float* __restrict__ prelu_a,
                               const float* __restrict__ w2, const float* __restrict__ b2,
                               const float* __restrict__ gcn_w, const float* __restrict__ wb,
                               const float* __restrict__ degf,
                               float* __restrict__ dinv, float* __restrict__ gs,
                               float* __restrict__ acc) {
    __shared__ float sA[32], sB[32], sC[32], sV[32], sU[32];
    __shared__ float sGB;
    if (threadIdx.x < 32) {
        int c = threadIdx.x;
        double invN = 1.0 / (double)N_NODES;
        double m0 = stats[0] * invN, m1 = stats[1] * invN;
        double e00 = stats[2] * invN, e11 = stats[3] * invN, e01 = stats[4] * invN;
        double a = w1[2 * c], b = w1[2 * c + 1], t = b1[c];
        double meanH = a * m0 + b * m1 + t;
        double eh2 = a * a * e00 + b * b * e11 + 2.0 * a * b * e01 +
                     2.0 * t * (a * m0 + b * m1) + t * t;
        double var = eh2 - meanH * meanH;
        double inv = 1.0 / sqrt(var + 1e-5);
        float sc = (float)((double)gamma[c] * inv);
        float shift = beta[c] - (float)meanH * sc;
        sA[c] = (float)a * sc;
        sB[c] = (float)b * sc;
        sC[c] = (float)t * sc + shift;
        float vc = 0.f;
        for (int j = 0; j < 32; j++) vc += wb[j] * gcn_w[j * 32 + c];
        sV[c] = vc;
        float gb = b2[c] * vc;
        for (int off = 16; off; off >>= 1) gb += __shfl_down(gb, off, 32);
        if (c == 0) sGB = gb;
    }
    __syncthreads();
    if (threadIdx.x < 32) {
        float u = 0.f;
        for (int c = 0; c < 32; c++) u += sV[c] * w2[c * 32 + threadIdx.x];
        sU[threadIdx.x] = u;
    }
    __syncthreads();
    float alpha = prelu_a[0];
    int n = blockIdx.x * blockDim.x + threadIdx.x;
    if (n < N_NODES) {
        float2 xv = ((const float2*)x)[n];
        float g = sGB;
#pragma unroll
        for (int c = 0; c < 32; c++) {
            float hb = sA[c] * xv.x + sB[c] * xv.y + sC[c];
            float pc = hb >= 0.f ? hb : alpha * hb;
            g += pc * sU[c];
        }
        float di = rsqrtf(degf[n] + 1.0f);
        float gg = di * g;
        dinv[n] = di;
        gs[n] = gg;
        acc[n] = gg;  // self-loop term; finalize multiplies by dinv
    }
}

// ---- K3: scatter histogram: dense gathers hoisted, branch-free ds_add ----
__global__ __launch_bounds__(T_HIST) void scatter_kernel(
        const void* __restrict__ ei, const float* __restrict__ gs,
        float* __restrict__ acc) {
    __shared__ float hist[HSZ];
    bool is64 = detect_is64(ei);
    const int tid = threadIdx.x;
    const int p = blockIdx.x >> 6;       // XCD-locality mapping
    const int slice = blockIdx.x & 63;
    const int base = p * PART;
    const unsigned trash = PART + (unsigned)(tid & 63);

    for (int i = tid; i < HSZ; i += T_HIST) hist[i] = 0.f;
    __syncthreads();

    int q0 = slice * SLICE_Q, q1 = q0 + SLICE_Q;
    if (is64) {
        const longlong2* sq = (const longlong2*)((const long long*)ei);
        const longlong2* dq = (const longlong2*)((const long long*)ei + N_EDGES);
#define SCE(sa, sb, da, db) { \
        float g0 = gs[(int)(sa).x]; \
        float g1 = gs[(int)(sa).y]; \
        float g2 = gs[(int)(sb).x]; \
        float g3 = gs[(int)(sb).y]; \
        unsigned l0 = (unsigned)((int)(da).x - base); \
        unsigned l1 = (unsigned)((int)(da).y - base); \
        unsigned l2 = (unsigned)((int)(db).x - base); \
        unsigned l3 = (unsigned)((int)(db).y - base); \
        atomicAdd(&hist[l0 < PART ? l0 : trash], g0); \
        atomicAdd(&hist[l1 < PART ? l1 : trash], g1); \
        atomicAdd(&hist[l2 < PART ? l2 : trash], g2); \
        atomicAdd(&hist[l3 < PART ? l3 : trash], g3); }
        int qb = q0;
        for (; qb + 2 * T_HIST <= q1; qb += 2 * T_HIST) {
            longlong2 sa0 = sq[2 * (qb + tid)],          sa1 = sq[2 * (qb + tid) + 1];
            longlong2 da0 = dq[2 * (qb + tid)],          da1 = dq[2 * (qb + tid) + 1];
            longlong2 sb0 = sq[2 * (qb + T_HIST + tid)], sb1 = sq[2 * (qb + T_HIST + tid) + 1];
            longlong2 db0 = dq[2 * (qb + T_HIST + tid)], db1 = dq[2 * (qb + T_HIST + tid) + 1];
            SCE(sa0, sa1, da0, da1)
            SCE(sb0, sb1, db0, db1)
        }
        for (int q = qb + tid; q < q1; q += T_HIST) {
            longlong2 sa0 = sq[2 * q], sa1 = sq[2 * q + 1];
            longlong2 da0 = dq[2 * q], da1 = dq[2 * q + 1];
            SCE(sa0, sa1, da0, da1)
        }
#undef SCE
    } else {
        const int4* sq = (const int4*)((const int*)ei);
        const int4* dq = (const int4*)((const int*)ei + N_EDGES);
#define SC4(S, D) { \
        float g0 = gs[(S).x]; \
        float g1 = gs[(S).y]; \
        float g2 = gs[(S).z]; \
        float g3 = gs[(S).w]; \
        unsigned l0 = (unsigned)((D).x - base); \
        unsigned l1 = (unsigned)((D).y - base); \
        unsigned l2 = (unsigned)((D).z - base); \
        unsigned l3 = (unsigned)((D).w - base); \
        atomicAdd(&hist[l0 < PART ? l0 : trash], g0); \
        atomicAdd(&hist[l1 < PART ? l1 : trash], g1); \
        atomicAdd(&hist[l2 < PART ? l2 : trash], g2); \
        atomicAdd(&hist[l3 < PART ? l3 : trash], g3); }
        int qb = q0;
        for (; qb + 2 * T_HIST <= q1; qb += 2 * T_HIST) {
            int4 sa = sq[qb + tid];
            int4 da = dq[qb + tid];
            int4 sb = sq[qb + T_HIST + tid];
            int4 db = dq[qb + T_HIST + tid];
            SC4(sa, da) SC4(sb, db)
        }
        for (int q = qb + tid; q < q1; q += T_HIST) {
            int4 sa = sq[q];
            int4 da = dq[q];
            SC4(sa, da)
        }
#undef SC4
    }
    __syncthreads();
    for (int i = tid; i < PART; i += T_HIST) {
        float v = hist[i];
        if (v != 0.f) unsafeAtomicAdd(&acc[base + i], v);
    }
}

// ---- K4: finalize: out = dinv*acc + const ----
__global__ void finalize_kernel(const float* __restrict__ dinv, const float* __restrict__ acc,
                                const float* __restrict__ gcn_b, const float* __restrict__ wb,
                                const float* __restrict__ bb, float* __restrict__ out) {
    __shared__ float scc;
    if (threadIdx.x < 32) {
        float pv = wb[threadIdx.x] * gcn_b[threadIdx.x];
        for (int off = 16; off; off >>= 1) pv += __shfl_down(pv, off, 32);
        if (threadIdx.x == 0) scc = pv + bb[0];
    }
    __syncthreads();
    int n = blockIdx.x * blockDim.x + threadIdx.x;
    if (n < N_NODES) out[n] = dinv[n] * acc[n] + scc;
}

extern "C" void kernel_launch(void* const* d_in, const int* in_sizes, int n_in,
                              void* d_out, int out_size, void* d_ws, size_t ws_size,
                              hipStream_t stream) {
    const float* x       = (const float*)d_in[0];
    const void*  ei      = d_in[1];
    const float* w1      = (const float*)d_in[2];
    const float* b1      = (const float*)d_in[3];
    const float* bn_g    = (const float*)d_in[4];
    const float* bn_b    = (const float*)d_in[5];
    const float* prelu_a = (const float*)d_in[6];
    const float* w2      = (const float*)d_in[7];
    const float* b2      = (const float*)d_in[8];
    const float* gcn_w   = (const float*)d_in[9];
    const float* gcn_b   = (const float*)d_in[10];
    const float* wb      = (const float*)d_in[11];
    const float* bb      = (const float*)d_in[12];
    float* out = (float*)d_out;

    char* base = (char*)d_ws;
    double* stats = (double*)(base + OFF_STATS);
    float*  degf  = (float*)(base + OFF_DEG);
    float*  acc   = (float*)(base + OFF_ACC);
    float*  dinv  = (float*)(base + OFF_DINV);
    float*  gs    = (float*)(base + OFF_GS);

    // zero stats + degf (acc[0,N) fully written by encoder; hist zero-skip covers the rest)
    hipMemsetAsync(d_ws, 0, OFF_DEG + PART * P_PARTS * 4, stream);

    stats_deg_kernel<<<BLOCKS_H, T_HIST, 0, stream>>>(x, ei, stats, degf);
    encoder_kernel<<<(N_NODES + 255) / 256, 256, 0, stream>>>(
        x, stats, w1, b1, bn_g, bn_b, prelu_a, w2, b2, gcn_w, wb, degf, dinv, gs, acc);
    scatter_kernel<<<BLOCKS_H, T_HIST, 0, stream>>>(ei, gs, acc);
    finalize_kernel<<<(N_NODES + 255) / 256, 256, 0, stream>>>(dinv, acc, gcn_b, wb, bb, out);
}

// Round 11
// 185.926 us; speedup vs baseline: 1.4945x; 1.4945x over previous
//
#include <hip/hip_runtime.h>

#define N_NODES 100000
#define N_EDGES 3200000
#define N_QUADS (N_EDGES / 4)            // 800000

// ---- hist geometry: P=4 partitions, 64 slices, 256 blocks, 1 block/CU ----
// XCD-locality: p = bid>>6, slice = bid&63 -> same-slice blocks {s,s+64,s+128,s+192}
// all land on the same XCD (64%8==0), slice data L2-resident after first touch.
// Atomics stay PREDICATED (sparse lanes): r10 measured dense-lane ds_add at
// ~2.75 cy/active-lane -> densifying quadrupled DS work and doubled the kernel.
#define P_PARTS  4
#define PART     25600                   // 4*25600 = 102400 >= N ; 102.4 KB LDS
#define SLICES   64
#define SLICE_Q  (N_QUADS / SLICES)      // 12500 quads per slice (exact)
#define BLOCKS_H (P_PARTS * SLICES)      // 256
#define T_HIST   1024

// ---------------- workspace layout (bytes) ----------------
#define OFF_STATS 0                      // double[5] (zeroed)
#define OFF_DEG   1024                   // float[102400] (zeroed)
#define OFF_ACC   410624                 // float[102400] (encoder writes [0,N))
#define OFF_DINV  820224                 // float[N]
#define OFF_GS    1220224                // float[N]
// total ~1.62 MB

// per-wave int64-vs-int32 detection: high words of first 64 int64 slots
__device__ __forceinline__ bool detect_is64(const void* ei) {
    const int* p = (const int*)ei;
    int lane = threadIdx.x & 63;
    int hi = p[2 * lane + 1];
    unsigned long long m = __ballot(hi != 0);
    return m == 0ull;  // wave-uniform
}

// ---- K1: degree histogram straight from int64 dst + BN stats (r9-identical) ----
__global__ __launch_bounds__(T_HIST) void stats_deg_kernel(
        const float* __restrict__ x, const void* __restrict__ ei,
        double* __restrict__ stats, float* __restrict__ degf) {
    __shared__ float hist[PART];
    bool is64 = detect_is64(ei);
    const int tid = threadIdx.x;
    const int p = blockIdx.x >> 6;       // XCD-locality mapping
    const int slice = blockIdx.x & 63;
    const int base = p * PART;

    for (int i = tid; i < PART; i += T_HIST) hist[i] = 0.f;
    __syncthreads();

    int q0 = slice * SLICE_Q, q1 = q0 + SLICE_Q;
#define DGE(va, vb) { \
        unsigned l0 = (unsigned)((int)(va).x - base); \
        unsigned l1 = (unsigned)((int)(va).y - base); \
        unsigned l2 = (unsigned)((int)(vb).x - base); \
        unsigned l3 = (unsigned)((int)(vb).y - base); \
        if (l0 < PART) atomicAdd(&hist[l0], 1.0f); \
        if (l1 < PART) atomicAdd(&hist[l1], 1.0f); \
        if (l2 < PART) atomicAdd(&hist[l2], 1.0f); \
        if (l3 < PART) atomicAdd(&hist[l3], 1.0f); }
    if (is64) {
        const longlong2* dq = (const longlong2*)((const long long*)ei + N_EDGES);
        int qb = q0;
        for (; qb + 4 * T_HIST <= q1; qb += 4 * T_HIST) {
            longlong2 a0 = dq[2 * (qb + tid)],              a1 = dq[2 * (qb + tid) + 1];
            longlong2 b0 = dq[2 * (qb + T_HIST + tid)],     b1 = dq[2 * (qb + T_HIST + tid) + 1];
            longlong2 c0 = dq[2 * (qb + 2 * T_HIST + tid)], c1 = dq[2 * (qb + 2 * T_HIST + tid) + 1];
            longlong2 d0 = dq[2 * (qb + 3 * T_HIST + tid)], d1 = dq[2 * (qb + 3 * T_HIST + tid) + 1];
            DGE(a0, a1) DGE(b0, b1) DGE(c0, c1) DGE(d0, d1)
        }
        for (int q = qb + tid; q < q1; q += T_HIST) {
            longlong2 a0 = dq[2 * q], a1 = dq[2 * q + 1];
            DGE(a0, a1)
        }
    } else {
        const int4* dq = (const int4*)((const int*)ei + N_EDGES);
        int qb = q0;
#define DG4(V) { \
        unsigned l0 = (unsigned)((V).x - base); \
        unsigned l1 = (unsigned)((V).y - base); \
        unsigned l2 = (unsigned)((V).z - base); \
        unsigned l3 = (unsigned)((V).w - base); \
        if (l0 < PART) atomicAdd(&hist[l0], 1.0f); \
        if (l1 < PART) atomicAdd(&hist[l1], 1.0f); \
        if (l2 < PART) atomicAdd(&hist[l2], 1.0f); \
        if (l3 < PART) atomicAdd(&hist[l3], 1.0f); }
        for (; qb + 4 * T_HIST <= q1; qb += 4 * T_HIST) {
            int4 a = dq[qb + tid];
            int4 b = dq[qb + T_HIST + tid];
            int4 c = dq[qb + 2 * T_HIST + tid];
            int4 d = dq[qb + 3 * T_HIST + tid];
            DG4(a) DG4(b) DG4(c) DG4(d)
        }
        for (int q = qb + tid; q < q1; q += T_HIST) { int4 a = dq[q]; DG4(a) }
#undef DG4
    }
#undef DGE
    __syncthreads();
    // flush: consecutive addresses -> coalescable global atomics; zero-skip
    for (int i = tid; i < PART; i += T_HIST) {
        float v = hist[i];
        if (v != 0.f) unsafeAtomicAdd(&degf[base + i], v);
    }

    // ---- BN stats over x (blocks covering node range only; block-uniform guard) ----
    if (blockIdx.x * T_HIST < N_NODES) {
        __shared__ double sh[5][T_HIST / 64];
        int n = blockIdx.x * T_HIST + tid;
        double a0 = 0, a1 = 0, a2 = 0, a3 = 0, a4 = 0;
        if (n < N_NODES) {
            float2 v = ((const float2*)x)[n];
            double x0 = v.x, x1 = v.y;
            a0 = x0; a1 = x1; a2 = x0 * x0; a3 = x1 * x1; a4 = x0 * x1;
        }
        for (int off = 32; off; off >>= 1) {
            a0 += __shfl_down(a0, off);
            a1 += __shfl_down(a1, off);
            a2 += __shfl_down(a2, off);
            a3 += __shfl_down(a3, off);
            a4 += __shfl_down(a4, off);
        }
        int w = tid >> 6;
        if ((tid & 63) == 0) {
            sh[0][w] = a0; sh[1][w] = a1; sh[2][w] = a2; sh[3][w] = a3; sh[4][w] = a4;
        }
        __syncthreads();
        if (tid == 0) {
            double t0 = 0, t1 = 0, t2 = 0, t3 = 0, t4 = 0;
            for (int i = 0; i < T_HIST / 64; i++) {
                t0 += sh[0][i]; t1 += sh[1][i]; t2 += sh[2][i]; t3 += sh[3][i]; t4 += sh[4][i];
            }
            atomicAdd(&stats[0], t0);
            atomicAdd(&stats[1], t1);
            atomicAdd(&stats[2], t2);
            atomicAdd(&stats[3], t3);
            atomicAdd(&stats[4], t4);
        }
    }
}

// ---- K2: encoder: gs[n] = dinv * (GB + sum_c PReLU(Ax0+Bx1+C) U[c]) ----
__global__ void encoder_kernel(const float* __restrict__ x,
                               const double* __restrict__ stats,
                               const float* __restrict__ w1, const float* __restrict__ b1,
                               const float* __restrict__ gamma, const float* __restrict__ beta,
                               const float* __restrict__ prelu_a,
                               const float* __restrict__ w2, const float* __restrict__ b2,
                               const float* __restrict__ gcn_w, const float* __restrict__ wb,
                               const float* __restrict__ degf,
                               float* __restrict__ dinv, float* __restrict__ gs,
                               float* __restrict__ acc) {
    __shared__ float sA[32], sB[32], sC[32], sV[32], sU[32];
    __shared__ float sGB;
    if (threadIdx.x < 32) {
        int c = threadIdx.x;
        double invN = 1.0 / (double)N_NODES;
        double m0 = stats[0] * invN, m1 = stats[1] * invN;
        double e00 = stats[2] * invN, e11 = stats[3] * invN, e01 = stats[4] * invN;
        double a = w1[2 * c], b = w1[2 * c + 1], t = b1[c];
        double meanH = a * m0 + b * m1 + t;
        double eh2 = a * a * e00 + b * b * e11 + 2.0 * a * b * e01 +
                     2.0 * t * (a * m0 + b * m1) + t * t;
        double var = eh2 - meanH * meanH;
        double inv = 1.0 / sqrt(var + 1e-5);
        float sc = (float)((double)gamma[c] * inv);
        float shift = beta[c] - (float)meanH * sc;
        sA[c] = (float)a * sc;
        sB[c] = (float)b * sc;
        sC[c] = (float)t * sc + shift;
        float vc = 0.f;
        for (int j = 0; j < 32; j++) vc += wb[j] * gcn_w[j * 32 + c];
        sV[c] = vc;
        float gb = b2[c] * vc;
        for (int off = 16; off; off >>= 1) gb += __shfl_down(gb, off, 32);
        if (c == 0) sGB = gb;
    }
    __syncthreads();
    if (threadIdx.x < 32) {
        float u = 0.f;
        for (int c = 0; c < 32; c++) u += sV[c] * w2[c * 32 + threadIdx.x];
        sU[threadIdx.x] = u;
    }
    __syncthreads();
    float alpha = prelu_a[0];
    int n = blockIdx.x * blockDim.x + threadIdx.x;
    if (n < N_NODES) {
        float2 xv = ((const float2*)x)[n];
        float g = sGB;
#pragma unroll
        for (int c = 0; c < 32; c++) {
            float hb = sA[c] * xv.x + sB[c] * xv.y + sC[c];
            float pc = hb >= 0.f ? hb : alpha * hb;
            g += pc * sU[c];
        }
        float di = rsqrtf(degf[n] + 1.0f);
        float gg = di * g;
        dinv[n] = di;
        gs[n] = gg;
        acc[n] = gg;  // self-loop term; finalize multiplies by dinv
    }
}

// ---- K3: scatter histogram: gathers issued dense-from-clamped-address FIRST
// (8 overlapping in flight, one ~300cy round-trip per iteration), then the
// predicated sparse ds_adds. Breaks r9's per-edge gather->ds serial chain. ----
__global__ __launch_bounds__(T_HIST) void scatter_kernel(
        const void* __restrict__ ei, const float* __restrict__ gs,
        float* __restrict__ acc) {
    __shared__ float hist[PART];
    bool is64 = detect_is64(ei);
    const int tid = threadIdx.x;
    const int p = blockIdx.x >> 6;       // XCD-locality mapping
    const int slice = blockIdx.x & 63;
    const int base = p * PART;

    for (int i = tid; i < PART; i += T_HIST) hist[i] = 0.f;
    __syncthreads();

    int q0 = slice * SLICE_Q, q1 = q0 + SLICE_Q;
    if (is64) {
        const longlong2* sq = (const longlong2*)((const long long*)ei);
        const longlong2* dq = (const longlong2*)((const long long*)ei + N_EDGES);
        // 2-quad-pair group: 8 edges. Gathers clamped to gs[0] when out of
        // partition (inactive lanes coalesce on one cacheline -> ~free).
#define SCE8(sa0, sa1, sb0, sb1, da0, da1, db0, db1) { \
        unsigned l0 = (unsigned)((int)(da0).x - base); \
        unsigned l1 = (unsigned)((int)(da0).y - base); \
        unsigned l2 = (unsigned)((int)(da1).x - base); \
        unsigned l3 = (unsigned)((int)(da1).y - base); \
        unsigned l4 = (unsigned)((int)(db0).x - base); \
        unsigned l5 = (unsigned)((int)(db0).y - base); \
        unsigned l6 = (unsigned)((int)(db1).x - base); \
        unsigned l7 = (unsigned)((int)(db1).y - base); \
        float g0 = gs[l0 < PART ? (int)(sa0).x : 0]; \
        float g1 = gs[l1 < PART ? (int)(sa0).y : 0]; \
        float g2 = gs[l2 < PART ? (int)(sa1).x : 0]; \
        float g3 = gs[l3 < PART ? (int)(sa1).y : 0]; \
        float g4 = gs[l4 < PART ? (int)(sb0).x : 0]; \
        float g5 = gs[l5 < PART ? (int)(sb0).y : 0]; \
        float g6 = gs[l6 < PART ? (int)(sb1).x : 0]; \
        float g7 = gs[l7 < PART ? (int)(sb1).y : 0]; \
        if (l0 < PART) atomicAdd(&hist[l0], g0); \
        if (l1 < PART) atomicAdd(&hist[l1], g1); \
        if (l2 < PART) atomicAdd(&hist[l2], g2); \
        if (l3 < PART) atomicAdd(&hist[l3], g3); \
        if (l4 < PART) atomicAdd(&hist[l4], g4); \
        if (l5 < PART) atomicAdd(&hist[l5], g5); \
        if (l6 < PART) atomicAdd(&hist[l6], g6); \
        if (l7 < PART) atomicAdd(&hist[l7], g7); }
        int qb = q0;
        for (; qb + 2 * T_HIST <= q1; qb += 2 * T_HIST) {
            longlong2 sa0 = sq[2 * (qb + tid)],          sa1 = sq[2 * (qb + tid) + 1];
            longlong2 da0 = dq[2 * (qb + tid)],          da1 = dq[2 * (qb + tid) + 1];
            longlong2 sb0 = sq[2 * (qb + T_HIST + tid)], sb1 = sq[2 * (qb + T_HIST + tid) + 1];
            longlong2 db0 = dq[2 * (qb + T_HIST + tid)], db1 = dq[2 * (qb + T_HIST + tid) + 1];
            SCE8(sa0, sa1, sb0, sb1, da0, da1, db0, db1)
        }
        for (int q = qb + tid; q < q1; q += T_HIST) {
            longlong2 sa0 = sq[2 * q], sa1 = sq[2 * q + 1];
            longlong2 da0 = dq[2 * q], da1 = dq[2 * q + 1];
            unsigned l0 = (unsigned)((int)da0.x - base);
            unsigned l1 = (unsigned)((int)da0.y - base);
            unsigned l2 = (unsigned)((int)da1.x - base);
            unsigned l3 = (unsigned)((int)da1.y - base);
            float g0 = gs[l0 < PART ? (int)sa0.x : 0];
            float g1 = gs[l1 < PART ? (int)sa0.y : 0];
            float g2 = gs[l2 < PART ? (int)sa1.x : 0];
            float g3 = gs[l3 < PART ? (int)sa1.y : 0];
            if (l0 < PART) atomicAdd(&hist[l0], g0);
            if (l1 < PART) atomicAdd(&hist[l1], g1);
            if (l2 < PART) atomicAdd(&hist[l2], g2);
            if (l3 < PART) atomicAdd(&hist[l3], g3);
        }
#undef SCE8
    } else {
        const int4* sq = (const int4*)((const int*)ei);
        const int4* dq = (const int4*)((const int*)ei + N_EDGES);
#define SC8(SA, SB, DA, DB) { \
        unsigned l0 = (unsigned)((DA).x - base); \
        unsigned l1 = (unsigned)((DA).y - base); \
        unsigned l2 = (unsigned)((DA).z - base); \
        unsigned l3 = (unsigned)((DA).w - base); \
        unsigned l4 = (unsigned)((DB).x - base); \
        unsigned l5 = (unsigned)((DB).y - base); \
        unsigned l6 = (unsigned)((DB).z - base); \
        unsigned l7 = (unsigned)((DB).w - base); \
        float g0 = gs[l0 < PART ? (SA).x : 0]; \
        float g1 = gs[l1 < PART ? (SA).y : 0]; \
        float g2 = gs[l2 < PART ? (SA).z : 0]; \
        float g3 = gs[l3 < PART ? (SA).w : 0]; \
        float g4 = gs[l4 < PART ? (SB).x : 0]; \
        float g5 = gs[l5 < PART ? (SB).y : 0]; \
        float g6 = gs[l6 < PART ? (SB).z : 0]; \
        float g7 = gs[l7 < PART ? (SB).w : 0]; \
        if (l0 < PART) atomicAdd(&hist[l0], g0); \
        if (l1 < PART) atomicAdd(&hist[l1], g1); \
        if (l2 < PART) atomicAdd(&hist[l2], g2); \
        if (l3 < PART) atomicAdd(&hist[l3], g3); \
        if (l4 < PART) atomicAdd(&hist[l4], g4); \
        if (l5 < PART) atomicAdd(&hist[l5], g5); \
        if (l6 < PART) atomicAdd(&hist[l6], g6); \
        if (l7 < PART) atomicAdd(&hist[l7], g7); }
        int qb = q0;
        for (; qb + 2 * T_HIST <= q1; qb += 2 * T_HIST) {
            int4 sa = sq[qb + tid];
            int4 da = dq[qb + tid];
            int4 sb = sq[qb + T_HIST + tid];
            int4 db = dq[qb + T_HIST + tid];
            SC8(sa, sb, da, db)
        }
        for (int q = qb + tid; q < q1; q += T_HIST) {
            int4 sa = sq[q];
            int4 da = dq[q];
            unsigned l0 = (unsigned)(da.x - base);
            unsigned l1 = (unsigned)(da.y - base);
            unsigned l2 = (unsigned)(da.z - base);
            unsigned l3 = (unsigned)(da.w - base);
            float g0 = gs[l0 < PART ? sa.x : 0];
            float g1 = gs[l1 < PART ? sa.y : 0];
            float g2 = gs[l2 < PART ? sa.z : 0];
            float g3 = gs[l3 < PART ? sa.w : 0];
            if (l0 < PART) atomicAdd(&hist[l0], g0);
            if (l1 < PART) atomicAdd(&hist[l1], g1);
            if (l2 < PART) atomicAdd(&hist[l2], g2);
            if (l3 < PART) atomicAdd(&hist[l3], g3);
        }
#undef SC8
    }
    __syncthreads();
    for (int i = tid; i < PART; i += T_HIST) {
        float v = hist[i];
        if (v != 0.f) unsafeAtomicAdd(&acc[base + i], v);
    }
}

// ---- K4: finalize: out = dinv*acc + const ----
__global__ void finalize_kernel(const float* __restrict__ dinv, const float* __restrict__ acc,
                                const float* __restrict__ gcn_b, const float* __restrict__ wb,
                                const float* __restrict__ bb, float* __restrict__ out) {
    __shared__ float scc;
    if (threadIdx.x < 32) {
        float pv = wb[threadIdx.x] * gcn_b[threadIdx.x];
        for (int off = 16; off; off >>= 1) pv += __shfl_down(pv, off, 32);
        if (threadIdx.x == 0) scc = pv + bb[0];
    }
    __syncthreads();
    int n = blockIdx.x * blockDim.x + threadIdx.x;
    if (n < N_NODES) out[n] = dinv[n] * acc[n] + scc;
}

extern "C" void kernel_launch(void* const* d_in, const int* in_sizes, int n_in,
                              void* d_out, int out_size, void* d_ws, size_t ws_size,
                              hipStream_t stream) {
    const float* x       = (const float*)d_in[0];
    const void*  ei      = d_in[1];
    const float* w1      = (const float*)d_in[2];
    const float* b1      = (const float*)d_in[3];
    const float* bn_g    = (const float*)d_in[4];
    const float* bn_b    = (const float*)d_in[5];
    const float* prelu_a = (const float*)d_in[6];
    const float* w2      = (const float*)d_in[7];
    const float* b2      = (const float*)d_in[8];
    const float* gcn_w   = (const float*)d_in[9];
    const float* gcn_b   = (const float*)d_in[10];
    const float* wb      = (const float*)d_in[11];
    const float* bb      = (const float*)d_in[12];
    float* out = (float*)d_out;

    char* base = (char*)d_ws;
    double* stats = (double*)(base + OFF_STATS);
    float*  degf  = (float*)(base + OFF_DEG);
    float*  acc   = (float*)(base + OFF_ACC);
    float*  dinv  = (float*)(base + OFF_DINV);
    float*  gs    = (float*)(base + OFF_GS);

    // zero stats + degf (acc[0,N) fully written by encoder; hist zero-skip covers the rest)
    hipMemsetAsync(d_ws, 0, OFF_DEG + PART * P_PARTS * 4, stream);

    stats_deg_kernel<<<BLOCKS_H, T_HIST, 0, stream>>>(x, ei, stats, degf);
    encoder_kernel<<<(N_NODES + 255) / 256, 256, 0, stream>>>(
        x, stats, w1, b1, bn_g, bn_b, prelu_a, w2, b2, gcn_w, wb, degf, dinv, gs, acc);
    scatter_kernel<<<BLOCKS_H, T_HIST, 0, stream>>>(ei, gs, acc);
    finalize_kernel<<<(N_NODES + 255) / 256, 256, 0, stream>>>(dinv, acc, gcn_b, wb, bb, out);
}

// Round 13
// 157.246 us; speedup vs baseline: 1.7671x; 1.1824x over previous
//
#include <hip/hip_runtime.h>

#define N_NODES 100000
#define N_EDGES 3200000
#define N_QUADS (N_EDGES / 4)            // 800000

// ---- hist geometry: P=4 partitions, 64 slices, 256 blocks, 1 block/CU ----
// XCD-locality: p = bid>>6, slice = bid&63 (same-slice blocks co-XCD, 64%8==0).
// FLUSH IS STREAMING, NOT ATOMIC: every round measured WRITE_SIZE=24.5MB from
// cross-block atomic-flush cacheline RMWs at ~0.69TB/s (r4 calibration) = ~35us
// of each 48us hist kernel. Blocks now store full partition hists to
// partial[slice][node] (disjoint -> plain float4 stores); consumers sum the 64
// slices (coalesced reads at streaming BW).
#define P_PARTS  4
#define PART     25600                   // 4*25600 = 102400 >= N ; 102.4 KB LDS
#define NTOT     (P_PARTS * PART)        // 102400
#define SLICES   64
#define SLICE_Q  (N_QUADS / SLICES)      // 12500 quads per slice (exact)
#define BLOCKS_H (P_PARTS * SLICES)      // 256
#define T_HIST   1024

// ---------------- workspace layout (bytes) ----------------
#define OFF_STATS   0                    // double[5] (zeroed, 1KB pad)
#define OFF_DINV    1024                 // float[N]
#define OFF_GS      401024               // float[N]
#define OFF_PARTIAL 801024               // float[64][102400] = 26.21MB, reused deg->scatter
// total 27,015,424 B (< 27.2MB proven footprint)

// per-wave int64-vs-int32 detection: high words of first 64 int64 slots
__device__ __forceinline__ bool detect_is64(const void* ei) {
    const int* p = (const int*)ei;
    int lane = threadIdx.x & 63;
    int hi = p[2 * lane + 1];
    unsigned long long m = __ballot(hi != 0);
    return m == 0ull;  // wave-uniform
}

// ---- K1: degree histogram -> streaming partial store + BN stats ----
__global__ __launch_bounds__(T_HIST) void stats_deg_kernel(
        const float* __restrict__ x, const void* __restrict__ ei,
        double* __restrict__ stats, float* __restrict__ partial) {
    __shared__ float hist[PART];
    bool is64 = detect_is64(ei);
    const int tid = threadIdx.x;
    const int p = blockIdx.x >> 6;       // XCD-locality mapping
    const int slice = blockIdx.x & 63;
    const int base = p * PART;

    for (int i = tid; i < PART; i += T_HIST) hist[i] = 0.f;
    __syncthreads();

    int q0 = slice * SLICE_Q, q1 = q0 + SLICE_Q;
#define DGE(va, vb) { \
        unsigned l0 = (unsigned)((int)(va).x - base); \
        unsigned l1 = (unsigned)((int)(va).y - base); \
        unsigned l2 = (unsigned)((int)(vb).x - base); \
        unsigned l3 = (unsigned)((int)(vb).y - base); \
        if (l0 < PART) atomicAdd(&hist[l0], 1.0f); \
        if (l1 < PART) atomicAdd(&hist[l1], 1.0f); \
        if (l2 < PART) atomicAdd(&hist[l2], 1.0f); \
        if (l3 < PART) atomicAdd(&hist[l3], 1.0f); }
    if (is64) {
        const longlong2* dq = (const longlong2*)((const long long*)ei + N_EDGES);
        int qb = q0;
        for (; qb + 4 * T_HIST <= q1; qb += 4 * T_HIST) {
            longlong2 a0 = dq[2 * (qb + tid)],              a1 = dq[2 * (qb + tid) + 1];
            longlong2 b0 = dq[2 * (qb + T_HIST + tid)],     b1 = dq[2 * (qb + T_HIST + tid) + 1];
            longlong2 c0 = dq[2 * (qb + 2 * T_HIST + tid)], c1 = dq[2 * (qb + 2 * T_HIST + tid) + 1];
            longlong2 d0 = dq[2 * (qb + 3 * T_HIST + tid)], d1 = dq[2 * (qb + 3 * T_HIST + tid) + 1];
            DGE(a0, a1) DGE(b0, b1) DGE(c0, c1) DGE(d0, d1)
        }
        for (int q = qb + tid; q < q1; q += T_HIST) {
            longlong2 a0 = dq[2 * q], a1 = dq[2 * q + 1];
            DGE(a0, a1)
        }
    } else {
        const int4* dq = (const int4*)((const int*)ei + N_EDGES);
        int qb = q0;
#define DG4(V) { \
        unsigned l0 = (unsigned)((V).x - base); \
        unsigned l1 = (unsigned)((V).y - base); \
        unsigned l2 = (unsigned)((V).z - base); \
        unsigned l3 = (unsigned)((V).w - base); \
        if (l0 < PART) atomicAdd(&hist[l0], 1.0f); \
        if (l1 < PART) atomicAdd(&hist[l1], 1.0f); \
        if (l2 < PART) atomicAdd(&hist[l2], 1.0f); \
        if (l3 < PART) atomicAdd(&hist[l3], 1.0f); }
        for (; qb + 4 * T_HIST <= q1; qb += 4 * T_HIST) {
            int4 a = dq[qb + tid];
            int4 b = dq[qb + T_HIST + tid];
            int4 c = dq[qb + 2 * T_HIST + tid];
            int4 d = dq[qb + 3 * T_HIST + tid];
            DG4(a) DG4(b) DG4(c) DG4(d)
        }
        for (int q = qb + tid; q < q1; q += T_HIST) { int4 a = dq[q]; DG4(a) }
#undef DG4
    }
#undef DGE
    __syncthreads();
    // streaming flush: full partition range, float4, no atomics
    {
        float4* dst = (float4*)(partial + (size_t)slice * NTOT + base);
        const float4* src = (const float4*)hist;
        for (int i = tid; i < PART / 4; i += T_HIST) dst[i] = src[i];
    }

    // ---- BN stats over x (blocks covering node range only; block-uniform guard) ----
    if (blockIdx.x * T_HIST < N_NODES) {
        __shared__ double sh[5][T_HIST / 64];
        int n = blockIdx.x * T_HIST + tid;
        double a0 = 0, a1 = 0, a2 = 0, a3 = 0, a4 = 0;
        if (n < N_NODES) {
            float2 v = ((const float2*)x)[n];
            double x0 = v.x, x1 = v.y;
            a0 = x0; a1 = x1; a2 = x0 * x0; a3 = x1 * x1; a4 = x0 * x1;
        }
        for (int off = 32; off; off >>= 1) {
            a0 += __shfl_down(a0, off);
            a1 += __shfl_down(a1, off);
            a2 += __shfl_down(a2, off);
            a3 += __shfl_down(a3, off);
            a4 += __shfl_down(a4, off);
        }
        int w = tid >> 6;
        if ((tid & 63) == 0) {
            sh[0][w] = a0; sh[1][w] = a1; sh[2][w] = a2; sh[3][w] = a3; sh[4][w] = a4;
        }
        __syncthreads();
        if (tid == 0) {
            double t0 = 0, t1 = 0, t2 = 0, t3 = 0, t4 = 0;
            for (int i = 0; i < T_HIST / 64; i++) {
                t0 += sh[0][i]; t1 += sh[1][i]; t2 += sh[2][i]; t3 += sh[3][i]; t4 += sh[4][i];
            }
            atomicAdd(&stats[0], t0);
            atomicAdd(&stats[1], t1);
            atomicAdd(&stats[2], t2);
            atomicAdd(&stats[3], t3);
            atomicAdd(&stats[4], t4);
        }
    }
}

// ---- K2: encoder: deg[n] = sum_s partial[s][n]; gs = dinv*(...) ----
__global__ void encoder_kernel(const float* __restrict__ x,
                               const double* __restrict__ stats,
                               const float* __restrict__ w1, const float* __restrict__ b1,
                               const float* __restrict__ gamma, const float* __restrict__ beta,
                               const float* __restrict__ prelu_a,
                               const float* __restrict__ w2, const float* __restrict__ b2,
                               const float* __restrict__ gcn_w, const float* __restrict__ wb,
                               const float* __restrict__ partial,
                               float* __restrict__ dinv, float* __restrict__ gs) {
    __shared__ float sA[32], sB[32], sC[32], sV[32], sU[32];
    __shared__ float sGB;
    if (threadIdx.x < 32) {
        int c = threadIdx.x;
        double invN = 1.0 / (double)N_NODES;
        double m0 = stats[0] * invN, m1 = stats[1] * invN;
        double e00 = stats[2] * invN, e11 = stats[3] * invN, e01 = stats[4] * invN;
        double a = w1[2 * c], b = w1[2 * c + 1], t = b1[c];
        double meanH = a * m0 + b * m1 + t;
        double eh2 = a * a * e00 + b * b * e11 + 2.0 * a * b * e01 +
                     2.0 * t * (a * m0 + b * m1) + t * t;
        double var = eh2 - meanH * meanH;
        double inv = 1.0 / sqrt(var + 1e-5);
        float sc = (float)((double)gamma[c] * inv);
        float shift = beta[c] - (float)meanH * sc;
        sA[c] = (float)a * sc;
        sB[c] = (float)b * sc;
        sC[c] = (float)t * sc + shift;
        float vc = 0.f;
        for (int j = 0; j < 32; j++) vc += wb[j] * gcn_w[j * 32 + c];
        sV[c] = vc;
        float gb = b2[c] * vc;
        for (int off = 16; off; off >>= 1) gb += __shfl_down(gb, off, 32);
        if (c == 0) sGB = gb;
    }
    __syncthreads();
    if (threadIdx.x < 32) {
        float u = 0.f;
        for (int c = 0; c < 32; c++) u += sV[c] * w2[c * 32 + threadIdx.x];
        sU[threadIdx.x] = u;
    }
    __syncthreads();
    float alpha = prelu_a[0];
    int n = blockIdx.x * blockDim.x + threadIdx.x;
    if (n < N_NODES) {
        // sum 64 deg-partials (coalesced across threads; 4-way ILP)
        const float* pd = partial + n;
        float d0 = 0.f, d1 = 0.f, d2 = 0.f, d3 = 0.f;
#pragma unroll
        for (int s = 0; s < SLICES; s += 4) {
            d0 += pd[(size_t)(s + 0) * NTOT];
            d1 += pd[(size_t)(s + 1) * NTOT];
            d2 += pd[(size_t)(s + 2) * NTOT];
            d3 += pd[(size_t)(s + 3) * NTOT];
        }
        float deg = (d0 + d1) + (d2 + d3);

        float2 xv = ((const float2*)x)[n];
        float g = sGB;
#pragma unroll
        for (int c = 0; c < 32; c++) {
            float hb = sA[c] * xv.x + sB[c] * xv.y + sC[c];
            float pc = hb >= 0.f ? hb : alpha * hb;
            g += pc * sU[c];
        }
        float di = rsqrtf(deg + 1.0f);
        dinv[n] = di;
        gs[n] = di * g;     // also the self-loop seed (dinv*gs = dinv^2*g)
    }
}

// ---- K3: scatter histogram -> streaming partial store ----
__global__ __launch_bounds__(T_HIST) void scatter_kernel(
        const void* __restrict__ ei, const float* __restrict__ gs,
        float* __restrict__ partial) {
    __shared__ float hist[PART];
    bool is64 = detect_is64(ei);
    const int tid = threadIdx.x;
    const int p = blockIdx.x >> 6;       // XCD-locality mapping
    const int slice = blockIdx.x & 63;
    const int base = p * PART;

    for (int i = tid; i < PART; i += T_HIST) hist[i] = 0.f;
    __syncthreads();

    int q0 = slice * SLICE_Q, q1 = q0 + SLICE_Q;
    if (is64) {
        const longlong2* sq = (const longlong2*)((const long long*)ei);
        const longlong2* dq = (const longlong2*)((const long long*)ei + N_EDGES);
#define SCE(sa, sb, da, db) { \
        unsigned l0 = (unsigned)((int)(da).x - base); \
        unsigned l1 = (unsigned)((int)(da).y - base); \
        unsigned l2 = (unsigned)((int)(db).x - base); \
        unsigned l3 = (unsigned)((int)(db).y - base); \
        if (l0 < PART) atomicAdd(&hist[l0], gs[(int)(sa).x]); \
        if (l1 < PART) atomicAdd(&hist[l1], gs[(int)(sa).y]); \
        if (l2 < PART) atomicAdd(&hist[l2], gs[(int)(sb).x]); \
        if (l3 < PART) atomicAdd(&hist[l3], gs[(int)(sb).y]); }
        int qb = q0;
        for (; qb + 2 * T_HIST <= q1; qb += 2 * T_HIST) {
            longlong2 sa0 = sq[2 * (qb + tid)],          sa1 = sq[2 * (qb + tid) + 1];
            longlong2 da0 = dq[2 * (qb + tid)],          da1 = dq[2 * (qb + tid) + 1];
            longlong2 sb0 = sq[2 * (qb + T_HIST + tid)], sb1 = sq[2 * (qb + T_HIST + tid) + 1];
            longlong2 db0 = dq[2 * (qb + T_HIST + tid)], db1 = dq[2 * (qb + T_HIST + tid) + 1];
            SCE(sa0, sa1, da0, da1)
            SCE(sb0, sb1, db0, db1)
        }
        for (int q = qb + tid; q < q1; q += T_HIST) {
            longlong2 sa0 = sq[2 * q], sa1 = sq[2 * q + 1];
            longlong2 da0 = dq[2 * q], da1 = dq[2 * q + 1];
            SCE(sa0, sa1, da0, da1)
        }
#undef SCE
    } else {
        const int4* sq = (const int4*)((const int*)ei);
        const int4* dq = (const int4*)((const int*)ei + N_EDGES);
#define SC4(S, D) { \
        unsigned l0 = (unsigned)((D).x - base); \
        unsigned l1 = (unsigned)((D).y - base); \
        unsigned l2 = (unsigned)((D).z - base); \
        unsigned l3 = (unsigned)((D).w - base); \
        if (l0 < PART) atomicAdd(&hist[l0], gs[(S).x]); \
        if (l1 < PART) atomicAdd(&hist[l1], gs[(S).y]); \
        if (l2 < PART) atomicAdd(&hist[l2], gs[(S).z]); \
        if (l3 < PART) atomicAdd(&hist[l3], gs[(S).w]); }
        int qb = q0;
        for (; qb + 2 * T_HIST <= q1; qb += 2 * T_HIST) {
            int4 sa = sq[qb + tid];
            int4 da = dq[qb + tid];
            int4 sb = sq[qb + T_HIST + tid];
            int4 db = dq[qb + T_HIST + tid];
            SC4(sa, da) SC4(sb, db)
        }
        for (int q = qb + tid; q < q1; q += T_HIST) {
            int4 sa = sq[q];
            int4 da = dq[q];
            SC4(sa, da)
        }
#undef SC4
    }
    __syncthreads();
    // streaming flush: full partition range, float4, no atomics
    {
        float4* dst = (float4*)(partial + (size_t)slice * NTOT + base);
        const float4* src = (const float4*)hist;
        for (int i = tid; i < PART / 4; i += T_HIST) dst[i] = src[i];
    }
}

// ---- K4: finalize: out = dinv*(gs + sum_s partial[s][n]) + const ----
__global__ void finalize_kernel(const float* __restrict__ dinv, const float* __restrict__ gs,
                                const float* __restrict__ partial,
                                const float* __restrict__ gcn_b, const float* __restrict__ wb,
                                const float* __restrict__ bb, float* __restrict__ out) {
    __shared__ float scc;
    if (threadIdx.x < 32) {
        float pv = wb[threadIdx.x] * gcn_b[threadIdx.x];
        for (int off = 16; off; off >>= 1) pv += __shfl_down(pv, off, 32);
        if (threadIdx.x == 0) scc = pv + bb[0];
    }
    __syncthreads();
    int n = blockIdx.x * blockDim.x + threadIdx.x;
    if (n < N_NODES) {
        const float* ps = partial + n;
        float a0 = 0.f, a1 = 0.f, a2 = 0.f, a3 = 0.f;
#pragma unroll
        for (int s = 0; s < SLICES; s += 4) {
            a0 += ps[(size_t)(s + 0) * NTOT];
            a1 += ps[(size_t)(s + 1) * NTOT];
            a2 += ps[(size_t)(s + 2) * NTOT];
            a3 += ps[(size_t)(s + 3) * NTOT];
        }
        float agg = gs[n] + (a0 + a1) + (a2 + a3);   // gs = self-loop seed
        out[n] = dinv[n] * agg + scc;
    }
}

extern "C" void kernel_launch(void* const* d_in, const int* in_sizes, int n_in,
                              void* d_out, int out_size, void* d_ws, size_t ws_size,
                              hipStream_t stream) {
    const float* x       = (const float*)d_in[0];
    const void*  ei      = d_in[1];
    const float* w1      = (const float*)d_in[2];
    const float* b1      = (const float*)d_in[3];
    const float* bn_g    = (const float*)d_in[4];
    const float* bn_b    = (const float*)d_in[5];
    const float* prelu_a = (const float*)d_in[6];
    const float* w2      = (const float*)d_in[7];
    const float* b2      = (const float*)d_in[8];
    const float* gcn_w   = (const float*)d_in[9];
    const float* gcn_b   = (const float*)d_in[10];
    const float* wb      = (const float*)d_in[11];
    const float* bb      = (const float*)d_in[12];
    float* out = (float*)d_out;

    char* base = (char*)d_ws;
    double* stats   = (double*)(base + OFF_STATS);
    float*  dinv    = (float*)(base + OFF_DINV);
    float*  gs      = (float*)(base + OFF_GS);
    float*  partial = (float*)(base + OFF_PARTIAL);  // deg partials, then scatter partials

    // zero stats only (partials are fully overwritten each pass)
    hipMemsetAsync(d_ws, 0, 1024, stream);

    stats_deg_kernel<<<BLOCKS_H, T_HIST, 0, stream>>>(x, ei, stats, partial);
    encoder_kernel<<<(N_NODES + 255) / 256, 256, 0, stream>>>(
        x, stats, w1, b1, bn_g, bn_b, prelu_a, w2, b2, gcn_w, wb, partial, dinv, gs);
    scatter_kernel<<<BLOCKS_H, T_HIST, 0, stream>>>(ei, gs, partial);
    finalize_kernel<<<(N_NODES + 255) / 256, 256, 0, stream>>>(
        dinv, gs, partial, gcn_b, wb, bb, out);
}

// Round 14
// 150.292 us; speedup vs baseline: 1.8489x; 1.0463x over previous
//
#include <hip/hip_runtime.h>

#define N_NODES 100000
#define N_EDGES 3200000
#define N_QUADS (N_EDGES / 4)            // 800000

// ---- geometry ----
// DEG pass: u8 hist covers ALL nodes in 102.4KB LDS -> P=1, each edge examined
// ONCE, no predication (every dst in range). 256 slice-blocks, 3125 quads each.
// SCATTER pass: float hist forces P=4 (25600 nodes/partition), 64 slices,
// XCD-locality p=bid>>6 slice=bid&63 (same-slice blocks co-XCD, 64%8==0).
// Both flush by STREAMING stores to disjoint partial rows (r13: atomic flush
// was ~35us of each 48us hist kernel; streaming fix measured -29us total).
#define NTOT     102400                  // padded node count (4*25600)
#define DSLICES  256
#define DSLICE_Q (N_QUADS / DSLICES)     // 3125 quads per deg slice (exact)
#define P_PARTS  4
#define PART     25600
#define SLICES   64
#define SLICE_Q  (N_QUADS / SLICES)      // 12500 quads per scatter slice
#define BLOCKS_H 256
#define T_HIST   1024

// ---------------- workspace layout (bytes) ----------------
#define OFF_STATS   0                    // double[5] (zeroed, 1KB pad)
#define OFF_DINV    1024                 // float[N]
#define OFF_GS      401024               // float[N]
#define OFF_PARTIAL 801024               // deg: u8[256][102400]; scatter: float[64][102400] (26.21MB, sequenced)
// total 27,015,424 B (< 27.2MB proven footprint)

// per-wave int64-vs-int32 detection: high words of first 64 int64 slots
__device__ __forceinline__ bool detect_is64(const void* ei) {
    const int* p = (const int*)ei;
    int lane = threadIdx.x & 63;
    int hi = p[2 * lane + 1];
    unsigned long long m = __ballot(hi != 0);
    return m == 0ull;  // wave-uniform
}

// ---- K1: single-pass u8 degree histogram -> streaming partial store + BN stats ----
__global__ __launch_bounds__(T_HIST) void stats_deg_kernel(
        const float* __restrict__ x, const void* __restrict__ ei,
        double* __restrict__ stats, unsigned char* __restrict__ partial8) {
    __shared__ unsigned int histw[NTOT / 4];   // u8 counts packed in u32; 102.4KB
    bool is64 = detect_is64(ei);
    const int tid = threadIdx.x;
    const int slice = blockIdx.x;              // 256 slices, P=1

    for (int i = tid; i < NTOT / 4; i += T_HIST) histw[i] = 0u;
    __syncthreads();

    int q0 = slice * DSLICE_Q, q1 = q0 + DSLICE_Q;
    // unconditional packed-byte add: word = n>>2, lane-byte = n&3
#define DADD(N) atomicAdd(&histw[(unsigned)(N) >> 2], 1u << (((unsigned)(N) & 3u) * 8u));
    if (is64) {
        const longlong2* dq = (const longlong2*)((const long long*)ei + N_EDGES);
        int qb = q0;
        for (; qb + 2 * T_HIST <= q1; qb += 2 * T_HIST) {
            longlong2 a0 = dq[2 * (qb + tid)],          a1 = dq[2 * (qb + tid) + 1];
            longlong2 b0 = dq[2 * (qb + T_HIST + tid)], b1 = dq[2 * (qb + T_HIST + tid) + 1];
            DADD((int)a0.x) DADD((int)a0.y) DADD((int)a1.x) DADD((int)a1.y)
            DADD((int)b0.x) DADD((int)b0.y) DADD((int)b1.x) DADD((int)b1.y)
        }
        for (int q = qb + tid; q < q1; q += T_HIST) {
            longlong2 a0 = dq[2 * q], a1 = dq[2 * q + 1];
            DADD((int)a0.x) DADD((int)a0.y) DADD((int)a1.x) DADD((int)a1.y)
        }
    } else {
        const int4* dq = (const int4*)((const int*)ei + N_EDGES);
        int qb = q0;
        for (; qb + 2 * T_HIST <= q1; qb += 2 * T_HIST) {
            int4 a = dq[qb + tid];
            int4 b = dq[qb + T_HIST + tid];
            DADD(a.x) DADD(a.y) DADD(a.z) DADD(a.w)
            DADD(b.x) DADD(b.y) DADD(b.z) DADD(b.w)
        }
        for (int q = qb + tid; q < q1; q += T_HIST) {
            int4 a = dq[q];
            DADD(a.x) DADD(a.y) DADD(a.z) DADD(a.w)
        }
    }
#undef DADD
    __syncthreads();
    // streaming flush: full u8 row, uint4 stores, no atomics
    {
        uint4* dst = (uint4*)(partial8 + (size_t)slice * NTOT);
        const uint4* src = (const uint4*)histw;
        for (int i = tid; i < NTOT / 16; i += T_HIST) dst[i] = src[i];
    }

    // ---- BN stats over x (blocks covering node range only; block-uniform guard) ----
    if (blockIdx.x * T_HIST < N_NODES) {
        __shared__ double sh[5][T_HIST / 64];
        int n = blockIdx.x * T_HIST + tid;
        double a0 = 0, a1 = 0, a2 = 0, a3 = 0, a4 = 0;
        if (n < N_NODES) {
            float2 v = ((const float2*)x)[n];
            double x0 = v.x, x1 = v.y;
            a0 = x0; a1 = x1; a2 = x0 * x0; a3 = x1 * x1; a4 = x0 * x1;
        }
        for (int off = 32; off; off >>= 1) {
            a0 += __shfl_down(a0, off);
            a1 += __shfl_down(a1, off);
            a2 += __shfl_down(a2, off);
            a3 += __shfl_down(a3, off);
            a4 += __shfl_down(a4, off);
        }
        int w = tid >> 6;
        if ((tid & 63) == 0) {
            sh[0][w] = a0; sh[1][w] = a1; sh[2][w] = a2; sh[3][w] = a3; sh[4][w] = a4;
        }
        __syncthreads();
        if (tid == 0) {
            double t0 = 0, t1 = 0, t2 = 0, t3 = 0, t4 = 0;
            for (int i = 0; i < T_HIST / 64; i++) {
                t0 += sh[0][i]; t1 += sh[1][i]; t2 += sh[2][i]; t3 += sh[3][i]; t4 += sh[4][i];
            }
            atomicAdd(&stats[0], t0);
            atomicAdd(&stats[1], t1);
            atomicAdd(&stats[2], t2);
            atomicAdd(&stats[3], t3);
            atomicAdd(&stats[4], t4);
        }
    }
}

// ---- K2: encoder: deg[n] = sum_s partial8[s][n] (256 u8 rows); gs = dinv*(...) ----
__global__ void encoder_kernel(const float* __restrict__ x,
                               const double* __restrict__ stats,
                               const float* __restrict__ w1, const float* __restrict__ b1,
                               const float* __restrict__ gamma, const float* __restrict__ beta,
                               const float* __restrict__ prelu_a,
                               const float* __restrict__ w2, const float* __restrict__ b2,
                               const float* __restrict__ gcn_w, const float* __restrict__ wb,
                               const unsigned char* __restrict__ partial8,
                               float* __restrict__ dinv, float* __restrict__ gs) {
    __shared__ float sA[32], sB[32], sC[32], sV[32], sU[32];
    __shared__ float sGB;
    if (threadIdx.x < 32) {
        int c = threadIdx.x;
        double invN = 1.0 / (double)N_NODES;
        double m0 = stats[0] * invN, m1 = stats[1] * invN;
        double e00 = stats[2] * invN, e11 = stats[3] * invN, e01 = stats[4] * invN;
        double a = w1[2 * c], b = w1[2 * c + 1], t = b1[c];
        double meanH = a * m0 + b * m1 + t;
        double eh2 = a * a * e00 + b * b * e11 + 2.0 * a * b * e01 +
                     2.0 * t * (a * m0 + b * m1) + t * t;
        double var = eh2 - meanH * meanH;
        double inv = 1.0 / sqrt(var + 1e-5);
        float sc = (float)((double)gamma[c] * inv);
        float shift = beta[c] - (float)meanH * sc;
        sA[c] = (float)a * sc;
        sB[c] = (float)b * sc;
        sC[c] = (float)t * sc + shift;
        float vc = 0.f;
        for (int j = 0; j < 32; j++) vc += wb[j] * gcn_w[j * 32 + c];
        sV[c] = vc;
        float gb = b2[c] * vc;
        for (int off = 16; off; off >>= 1) gb += __shfl_down(gb, off, 32);
        if (c == 0) sGB = gb;
    }
    __syncthreads();
    if (threadIdx.x < 32) {
        float u = 0.f;
        for (int c = 0; c < 32; c++) u += sV[c] * w2[c * 32 + threadIdx.x];
        sU[threadIdx.x] = u;
    }
    __syncthreads();
    float alpha = prelu_a[0];
    int n = blockIdx.x * blockDim.x + threadIdx.x;
    if (n < N_NODES) {
        // sum 256 u8 deg-partials (coalesced byte rows; 4-way ILP)
        const unsigned char* pd = partial8 + n;
        unsigned d0 = 0, d1 = 0, d2 = 0, d3 = 0;
#pragma unroll
        for (int s = 0; s < DSLICES; s += 4) {
            d0 += pd[(size_t)(s + 0) * NTOT];
            d1 += pd[(size_t)(s + 1) * NTOT];
            d2 += pd[(size_t)(s + 2) * NTOT];
            d3 += pd[(size_t)(s + 3) * NTOT];
        }
        float deg = (float)((d0 + d1) + (d2 + d3));

        float2 xv = ((const float2*)x)[n];
        float g = sGB;
#pragma unroll
        for (int c = 0; c < 32; c++) {
            float hb = sA[c] * xv.x + sB[c] * xv.y + sC[c];
            float pc = hb >= 0.f ? hb : alpha * hb;
            g += pc * sU[c];
        }
        float di = rsqrtf(deg + 1.0f);
        dinv[n] = di;
        gs[n] = di * g;     // also the self-loop seed (dinv*gs = dinv^2*g)
    }
}

// ---- K3: scatter histogram (P=4 float) -> streaming partial store ----
__global__ __launch_bounds__(T_HIST) void scatter_kernel(
        const void* __restrict__ ei, const float* __restrict__ gs,
        float* __restrict__ partial) {
    __shared__ float hist[PART];
    bool is64 = detect_is64(ei);
    const int tid = threadIdx.x;
    const int p = blockIdx.x >> 6;       // XCD-locality mapping
    const int slice = blockIdx.x & 63;
    const int base = p * PART;

    for (int i = tid; i < PART; i += T_HIST) hist[i] = 0.f;
    __syncthreads();

    int q0 = slice * SLICE_Q, q1 = q0 + SLICE_Q;
    if (is64) {
        const longlong2* sq = (const longlong2*)((const long long*)ei);
        const longlong2* dq = (const longlong2*)((const long long*)ei + N_EDGES);
#define SCE(sa, sb, da, db) { \
        unsigned l0 = (unsigned)((int)(da).x - base); \
        unsigned l1 = (unsigned)((int)(da).y - base); \
        unsigned l2 = (unsigned)((int)(db).x - base); \
        unsigned l3 = (unsigned)((int)(db).y - base); \
        if (l0 < PART) atomicAdd(&hist[l0], gs[(int)(sa).x]); \
        if (l1 < PART) atomicAdd(&hist[l1], gs[(int)(sa).y]); \
        if (l2 < PART) atomicAdd(&hist[l2], gs[(int)(sb).x]); \
        if (l3 < PART) atomicAdd(&hist[l3], gs[(int)(sb).y]); }
        int qb = q0;
        for (; qb + 2 * T_HIST <= q1; qb += 2 * T_HIST) {
            longlong2 sa0 = sq[2 * (qb + tid)],          sa1 = sq[2 * (qb + tid) + 1];
            longlong2 da0 = dq[2 * (qb + tid)],          da1 = dq[2 * (qb + tid) + 1];
            longlong2 sb0 = sq[2 * (qb + T_HIST + tid)], sb1 = sq[2 * (qb + T_HIST + tid) + 1];
            longlong2 db0 = dq[2 * (qb + T_HIST + tid)], db1 = dq[2 * (qb + T_HIST + tid) + 1];
            SCE(sa0, sa1, da0, da1)
            SCE(sb0, sb1, db0, db1)
        }
        for (int q = qb + tid; q < q1; q += T_HIST) {
            longlong2 sa0 = sq[2 * q], sa1 = sq[2 * q + 1];
            longlong2 da0 = dq[2 * q], da1 = dq[2 * q + 1];
            SCE(sa0, sa1, da0, da1)
        }
#undef SCE
    } else {
        const int4* sq = (const int4*)((const int*)ei);
        const int4* dq = (const int4*)((const int*)ei + N_EDGES);
#define SC4(S, D) { \
        unsigned l0 = (unsigned)((D).x - base); \
        unsigned l1 = (unsigned)((D).y - base); \
        unsigned l2 = (unsigned)((D).z - base); \
        unsigned l3 = (unsigned)((D).w - base); \
        if (l0 < PART) atomicAdd(&hist[l0], gs[(S).x]); \
        if (l1 < PART) atomicAdd(&hist[l1], gs[(S).y]); \
        if (l2 < PART) atomicAdd(&hist[l2], gs[(S).z]); \
        if (l3 < PART) atomicAdd(&hist[l3], gs[(S).w]); }
        int qb = q0;
        for (; qb + 2 * T_HIST <= q1; qb += 2 * T_HIST) {
            int4 sa = sq[qb + tid];
            int4 da = dq[qb + tid];
            int4 sb = sq[qb + T_HIST + tid];
            int4 db = dq[qb + T_HIST + tid];
            SC4(sa, da) SC4(sb, db)
        }
        for (int q = qb + tid; q < q1; q += T_HIST) {
            int4 sa = sq[q];
            int4 da = dq[q];
            SC4(sa, da)
        }
#undef SC4
    }
    __syncthreads();
    // streaming flush: full partition range, float4, no atomics
    {
        float4* dst = (float4*)(partial + (size_t)slice * NTOT + base);
        const float4* src = (const float4*)hist;
        for (int i = tid; i < PART / 4; i += T_HIST) dst[i] = src[i];
    }
}

// ---- K4: finalize: out = dinv*(gs + sum_s partial[s][n]) + const ----
__global__ void finalize_kernel(const float* __restrict__ dinv, const float* __restrict__ gs,
                                const float* __restrict__ partial,
                                const float* __restrict__ gcn_b, const float* __restrict__ wb,
                                const float* __restrict__ bb, float* __restrict__ out) {
    __shared__ float scc;
    if (threadIdx.x < 32) {
        float pv = wb[threadIdx.x] * gcn_b[threadIdx.x];
        for (int off = 16; off; off >>= 1) pv += __shfl_down(pv, off, 32);
        if (threadIdx.x == 0) scc = pv + bb[0];
    }
    __syncthreads();
    int n = blockIdx.x * blockDim.x + threadIdx.x;
    if (n < N_NODES) {
        const float* ps = partial + n;
        float a0 = 0.f, a1 = 0.f, a2 = 0.f, a3 = 0.f;
#pragma unroll
        for (int s = 0; s < SLICES; s += 4) {
            a0 += ps[(size_t)(s + 0) * NTOT];
            a1 += ps[(size_t)(s + 1) * NTOT];
            a2 += ps[(size_t)(s + 2) * NTOT];
            a3 += ps[(size_t)(s + 3) * NTOT];
        }
        float agg = gs[n] + (a0 + a1) + (a2 + a3);   // gs = self-loop seed
        out[n] = dinv[n] * agg + scc;
    }
}

extern "C" void kernel_launch(void* const* d_in, const int* in_sizes, int n_in,
                              void* d_out, int out_size, void* d_ws, size_t ws_size,
                              hipStream_t stream) {
    const float* x       = (const float*)d_in[0];
    const void*  ei      = d_in[1];
    const float* w1      = (const float*)d_in[2];
    const float* b1      = (const float*)d_in[3];
    const float* bn_g    = (const float*)d_in[4];
    const float* bn_b    = (const float*)d_in[5];
    const float* prelu_a = (const float*)d_in[6];
    const float* w2      = (const float*)d_in[7];
    const float* b2      = (const float*)d_in[8];
    const float* gcn_w   = (const float*)d_in[9];
    const float* gcn_b   = (const float*)d_in[10];
    const float* wb      = (const float*)d_in[11];
    const float* bb      = (const float*)d_in[12];
    float* out = (float*)d_out;

    char* base = (char*)d_ws;
    double*        stats    = (double*)(base + OFF_STATS);
    float*         dinv     = (float*)(base + OFF_DINV);
    float*         gs       = (float*)(base + OFF_GS);
    unsigned char* partial8 = (unsigned char*)(base + OFF_PARTIAL);
    float*         partial  = (float*)(base + OFF_PARTIAL);   // reused after encoder reads u8

    // zero stats only (partials fully overwritten each pass)
    hipMemsetAsync(d_ws, 0, 1024, stream);

    stats_deg_kernel<<<DSLICES, T_HIST, 0, stream>>>(x, ei, stats, partial8);
    encoder_kernel<<<(N_NODES + 255) / 256, 256, 0, stream>>>(
        x, stats, w1, b1, bn_g, bn_b, prelu_a, w2, b2, gcn_w, wb, partial8, dinv, gs);
    scatter_kernel<<<BLOCKS_H, T_HIST, 0, stream>>>(ei, gs, partial);
    finalize_kernel<<<(N_NODES + 255) / 256, 256, 0, stream>>>(
        dinv, gs, partial, gcn_b, wb, bb, out);
}

// Round 15
// 146.761 us; speedup vs baseline: 1.8934x; 1.0241x over previous
//
#include <hip/hip_runtime.h>

#define N_NODES 100000
#define N_EDGES 3200000
#define N_QUADS (N_EDGES / 4)            // 800000

// ---- geometry ----
// DEG pass: u8 hist covers ALL nodes in 102.4KB LDS -> P=1, each edge examined
// ONCE, no predication. 256 slice-blocks, 3125 quads each.
// SCATTER pass: float hist forces P=4 (25600 nodes/partition), 64 slices,
// XCD-locality p=bid>>6 slice=bid&63 (same-slice blocks co-XCD, 64%8==0).
// Both flush by STREAMING stores to disjoint partial rows (r13: atomic flush
// was ~35us/kernel; streaming fix measured -29us total).
// r15: 4-quad ILP unroll in main loops (latency exposure was the residual;
// occupancy is LDS-capped at 16 waves/CU so per-wave MLP is the lever).
#define NTOT     102400                  // padded node count (4*25600)
#define DSLICES  256
#define DSLICE_Q (N_QUADS / DSLICES)     // 3125 quads per deg slice (exact)
#define P_PARTS  4
#define PART     25600
#define SLICES   64
#define SLICE_Q  (N_QUADS / SLICES)      // 12500 quads per scatter slice
#define BLOCKS_H 256
#define T_HIST   1024

// ---------------- workspace layout (bytes) ----------------
#define OFF_STATS   0                    // double[5] (zeroed, 1KB pad)
#define OFF_DINV    1024                 // float[N]
#define OFF_GS      401024               // float[N]
#define OFF_PARTIAL 801024               // deg: u8[256][102400]; scatter: float[64][102400] (26.21MB, sequenced)
// total 27,015,424 B (< 27.2MB proven footprint)

// per-wave int64-vs-int32 detection: high words of first 64 int64 slots
__device__ __forceinline__ bool detect_is64(const void* ei) {
    const int* p = (const int*)ei;
    int lane = threadIdx.x & 63;
    int hi = p[2 * lane + 1];
    unsigned long long m = __ballot(hi != 0);
    return m == 0ull;  // wave-uniform
}

// ---- K1: single-pass u8 degree histogram -> streaming partial store + BN stats ----
__global__ __launch_bounds__(T_HIST) void stats_deg_kernel(
        const float* __restrict__ x, const void* __restrict__ ei,
        double* __restrict__ stats, unsigned char* __restrict__ partial8) {
    __shared__ unsigned int histw[NTOT / 4];   // u8 counts packed in u32; 102.4KB
    bool is64 = detect_is64(ei);
    const int tid = threadIdx.x;
    const int slice = blockIdx.x;              // 256 slices, P=1

    {   // vector zero
        uint4 z = make_uint4(0u, 0u, 0u, 0u);
        uint4* hz = (uint4*)histw;
        for (int i = tid; i < NTOT / 16; i += T_HIST) hz[i] = z;
    }
    __syncthreads();

    int q0 = slice * DSLICE_Q, q1 = q0 + DSLICE_Q;
    // unconditional packed-byte add: word = n>>2, lane-byte = n&3
#define DADD(N) atomicAdd(&histw[(unsigned)(N) >> 2], 1u << (((unsigned)(N) & 3u) * 8u));
    if (is64) {
        const longlong2* dq = (const longlong2*)((const long long*)ei + N_EDGES);
        int qb = q0;
        for (; qb + 4 * T_HIST <= q1; qb += 4 * T_HIST) {   // 4-quad ILP
            longlong2 a0 = dq[2 * (qb + tid)],              a1 = dq[2 * (qb + tid) + 1];
            longlong2 b0 = dq[2 * (qb + T_HIST + tid)],     b1 = dq[2 * (qb + T_HIST + tid) + 1];
            longlong2 c0 = dq[2 * (qb + 2 * T_HIST + tid)], c1 = dq[2 * (qb + 2 * T_HIST + tid) + 1];
            longlong2 d0 = dq[2 * (qb + 3 * T_HIST + tid)], d1 = dq[2 * (qb + 3 * T_HIST + tid) + 1];
            DADD((int)a0.x) DADD((int)a0.y) DADD((int)a1.x) DADD((int)a1.y)
            DADD((int)b0.x) DADD((int)b0.y) DADD((int)b1.x) DADD((int)b1.y)
            DADD((int)c0.x) DADD((int)c0.y) DADD((int)c1.x) DADD((int)c1.y)
            DADD((int)d0.x) DADD((int)d0.y) DADD((int)d1.x) DADD((int)d1.y)
        }
        for (int q = qb + tid; q < q1; q += T_HIST) {
            longlong2 a0 = dq[2 * q], a1 = dq[2 * q + 1];
            DADD((int)a0.x) DADD((int)a0.y) DADD((int)a1.x) DADD((int)a1.y)
        }
    } else {
        const int4* dq = (const int4*)((const int*)ei + N_EDGES);
        int qb = q0;
        for (; qb + 4 * T_HIST <= q1; qb += 4 * T_HIST) {   // 4-quad ILP
            int4 a = dq[qb + tid];
            int4 b = dq[qb + T_HIST + tid];
            int4 c = dq[qb + 2 * T_HIST + tid];
            int4 d = dq[qb + 3 * T_HIST + tid];
            DADD(a.x) DADD(a.y) DADD(a.z) DADD(a.w)
            DADD(b.x) DADD(b.y) DADD(b.z) DADD(b.w)
            DADD(c.x) DADD(c.y) DADD(c.z) DADD(c.w)
            DADD(d.x) DADD(d.y) DADD(d.z) DADD(d.w)
        }
        for (int q = qb + tid; q < q1; q += T_HIST) {
            int4 a = dq[q];
            DADD(a.x) DADD(a.y) DADD(a.z) DADD(a.w)
        }
    }
#undef DADD
    __syncthreads();
    // streaming flush: full u8 row, uint4 stores, no atomics
    {
        uint4* dst = (uint4*)(partial8 + (size_t)slice * NTOT);
        const uint4* src = (const uint4*)histw;
        for (int i = tid; i < NTOT / 16; i += T_HIST) dst[i] = src[i];
    }

    // ---- BN stats over x (blocks covering node range only; block-uniform guard) ----
    if (blockIdx.x * T_HIST < N_NODES) {
        __shared__ double sh[5][T_HIST / 64];
        int n = blockIdx.x * T_HIST + tid;
        double a0 = 0, a1 = 0, a2 = 0, a3 = 0, a4 = 0;
        if (n < N_NODES) {
            float2 v = ((const float2*)x)[n];
            double x0 = v.x, x1 = v.y;
            a0 = x0; a1 = x1; a2 = x0 * x0; a3 = x1 * x1; a4 = x0 * x1;
        }
        for (int off = 32; off; off >>= 1) {
            a0 += __shfl_down(a0, off);
            a1 += __shfl_down(a1, off);
            a2 += __shfl_down(a2, off);
            a3 += __shfl_down(a3, off);
            a4 += __shfl_down(a4, off);
        }
        int w = tid >> 6;
        if ((tid & 63) == 0) {
            sh[0][w] = a0; sh[1][w] = a1; sh[2][w] = a2; sh[3][w] = a3; sh[4][w] = a4;
        }
        __syncthreads();
        if (tid == 0) {
            double t0 = 0, t1 = 0, t2 = 0, t3 = 0, t4 = 0;
            for (int i = 0; i < T_HIST / 64; i++) {
                t0 += sh[0][i]; t1 += sh[1][i]; t2 += sh[2][i]; t3 += sh[3][i]; t4 += sh[4][i];
            }
            atomicAdd(&stats[0], t0);
            atomicAdd(&stats[1], t1);
            atomicAdd(&stats[2], t2);
            atomicAdd(&stats[3], t3);
            atomicAdd(&stats[4], t4);
        }
    }
}

// ---- K2: encoder: deg[n] = sum_s partial8[s][n] (256 u8 rows); gs = dinv*(...) ----
__global__ void encoder_kernel(const float* __restrict__ x,
                               const double* __restrict__ stats,
                               const float* __restrict__ w1, const float* __restrict__ b1,
                               const float* __restrict__ gamma, const float* __restrict__ beta,
                               const float* __restrict__ prelu_a,
                               const float* __restrict__ w2, const float* __restrict__ b2,
                               const float* __restrict__ gcn_w, const float* __restrict__ wb,
                               const unsigned char* __restrict__ partial8,
                               float* __restrict__ dinv, float* __restrict__ gs) {
    __shared__ float sA[32], sB[32], sC[32], sV[32], sU[32];
    __shared__ float sGB;
    if (threadIdx.x < 32) {
        int c = threadIdx.x;
        double invN = 1.0 / (double)N_NODES;
        double m0 = stats[0] * invN, m1 = stats[1] * invN;
        double e00 = stats[2] * invN, e11 = stats[3] * invN, e01 = stats[4] * invN;
        double a = w1[2 * c], b = w1[2 * c + 1], t = b1[c];
        double meanH = a * m0 + b * m1 + t;
        double eh2 = a * a * e00 + b * b * e11 + 2.0 * a * b * e01 +
                     2.0 * t * (a * m0 + b * m1) + t * t;
        double var = eh2 - meanH * meanH;
        double inv = 1.0 / sqrt(var + 1e-5);
        float sc = (float)((double)gamma[c] * inv);
        float shift = beta[c] - (float)meanH * sc;
        sA[c] = (float)a * sc;
        sB[c] = (float)b * sc;
        sC[c] = (float)t * sc + shift;
        float vc = 0.f;
        for (int j = 0; j < 32; j++) vc += wb[j] * gcn_w[j * 32 + c];
        sV[c] = vc;
        float gb = b2[c] * vc;
        for (int off = 16; off; off >>= 1) gb += __shfl_down(gb, off, 32);
        if (c == 0) sGB = gb;
    }
    __syncthreads();
    if (threadIdx.x < 32) {
        float u = 0.f;
        for (int c = 0; c < 32; c++) u += sV[c] * w2[c * 32 + threadIdx.x];
        sU[threadIdx.x] = u;
    }
    __syncthreads();
    float alpha = prelu_a[0];
    int n = blockIdx.x * blockDim.x + threadIdx.x;
    if (n < N_NODES) {
        // sum 256 u8 deg-partials (coalesced byte rows; 4-way ILP)
        const unsigned char* pd = partial8 + n;
        unsigned d0 = 0, d1 = 0, d2 = 0, d3 = 0;
#pragma unroll
        for (int s = 0; s < DSLICES; s += 4) {
            d0 += pd[(size_t)(s + 0) * NTOT];
            d1 += pd[(size_t)(s + 1) * NTOT];
            d2 += pd[(size_t)(s + 2) * NTOT];
            d3 += pd[(size_t)(s + 3) * NTOT];
        }
        float deg = (float)((d0 + d1) + (d2 + d3));

        float2 xv = ((const float2*)x)[n];
        float g = sGB;
#pragma unroll
        for (int c = 0; c < 32; c++) {
            float hb = sA[c] * xv.x + sB[c] * xv.y + sC[c];
            float pc = hb >= 0.f ? hb : alpha * hb;
            g += pc * sU[c];
        }
        float di = rsqrtf(deg + 1.0f);
        dinv[n] = di;
        gs[n] = di * g;     // also the self-loop seed (dinv*gs = dinv^2*g)
    }
}

// ---- K3: scatter histogram (P=4 float, 4-quad ILP) -> streaming partial store ----
__global__ __launch_bounds__(T_HIST) void scatter_kernel(
        const void* __restrict__ ei, const float* __restrict__ gs,
        float* __restrict__ partial) {
    __shared__ float hist[PART];
    bool is64 = detect_is64(ei);
    const int tid = threadIdx.x;
    const int p = blockIdx.x >> 6;       // XCD-locality mapping
    const int slice = blockIdx.x & 63;
    const int base = p * PART;

    {   // vector zero
        float4 z = make_float4(0.f, 0.f, 0.f, 0.f);
        float4* hz = (float4*)hist;
        for (int i = tid; i < PART / 4; i += T_HIST) hz[i] = z;
    }
    __syncthreads();

    int q0 = slice * SLICE_Q, q1 = q0 + SLICE_Q;
    if (is64) {
        const longlong2* sq = (const longlong2*)((const long long*)ei);
        const longlong2* dq = (const longlong2*)((const long long*)ei + N_EDGES);
#define SCE(sa, sb, da, db) { \
        unsigned l0 = (unsigned)((int)(da).x - base); \
        unsigned l1 = (unsigned)((int)(da).y - base); \
        unsigned l2 = (unsigned)((int)(db).x - base); \
        unsigned l3 = (unsigned)((int)(db).y - base); \
        if (l0 < PART) atomicAdd(&hist[l0], gs[(int)(sa).x]); \
        if (l1 < PART) atomicAdd(&hist[l1], gs[(int)(sa).y]); \
        if (l2 < PART) atomicAdd(&hist[l2], gs[(int)(sb).x]); \
        if (l3 < PART) atomicAdd(&hist[l3], gs[(int)(sb).y]); }
        int qb = q0;
        for (; qb + 4 * T_HIST <= q1; qb += 4 * T_HIST) {   // 4-quad ILP
            longlong2 sa0 = sq[2 * (qb + tid)],              sa1 = sq[2 * (qb + tid) + 1];
            longlong2 da0 = dq[2 * (qb + tid)],              da1 = dq[2 * (qb + tid) + 1];
            longlong2 sb0 = sq[2 * (qb + T_HIST + tid)],     sb1 = sq[2 * (qb + T_HIST + tid) + 1];
            longlong2 db0 = dq[2 * (qb + T_HIST + tid)],     db1 = dq[2 * (qb + T_HIST + tid) + 1];
            longlong2 sc0 = sq[2 * (qb + 2 * T_HIST + tid)], sc1 = sq[2 * (qb + 2 * T_HIST + tid) + 1];
            longlong2 dc0 = dq[2 * (qb + 2 * T_HIST + tid)], dc1 = dq[2 * (qb + 2 * T_HIST + tid) + 1];
            longlong2 sd0 = sq[2 * (qb + 3 * T_HIST + tid)], sd1 = sq[2 * (qb + 3 * T_HIST + tid) + 1];
            longlong2 dd0 = dq[2 * (qb + 3 * T_HIST + tid)], dd1 = dq[2 * (qb + 3 * T_HIST + tid) + 1];
            SCE(sa0, sa1, da0, da1)
            SCE(sb0, sb1, db0, db1)
            SCE(sc0, sc1, dc0, dc1)
            SCE(sd0, sd1, dd0, dd1)
        }
        for (int q = qb + tid; q < q1; q += T_HIST) {
            longlong2 sa0 = sq[2 * q], sa1 = sq[2 * q + 1];
            longlong2 da0 = dq[2 * q], da1 = dq[2 * q + 1];
            SCE(sa0, sa1, da0, da1)
        }
#undef SCE
    } else {
        const int4* sq = (const int4*)((const int*)ei);
        const int4* dq = (const int4*)((const int*)ei + N_EDGES);
#define SC4(S, D) { \
        unsigned l0 = (unsigned)((D).x - base); \
        unsigned l1 = (unsigned)((D).y - base); \
        unsigned l2 = (unsigned)((D).z - base); \
        unsigned l3 = (unsigned)((D).w - base); \
        if (l0 < PART) atomicAdd(&hist[l0], gs[(S).x]); \
        if (l1 < PART) atomicAdd(&hist[l1], gs[(S).y]); \
        if (l2 < PART) atomicAdd(&hist[l2], gs[(S).z]); \
        if (l3 < PART) atomicAdd(&hist[l3], gs[(S).w]); }
        int qb = q0;
        for (; qb + 4 * T_HIST <= q1; qb += 4 * T_HIST) {   // 4-quad ILP
            int4 sa = sq[qb + tid];
            int4 da = dq[qb + tid];
            int4 sb = sq[qb + T_HIST + tid];
            int4 db = dq[qb + T_HIST + tid];
            int4 sc = sq[qb + 2 * T_HIST + tid];
            int4 dc = dq[qb + 2 * T_HIST + tid];
            int4 sd = sq[qb + 3 * T_HIST + tid];
            int4 dd = dq[qb + 3 * T_HIST + tid];
            SC4(sa, da) SC4(sb, db) SC4(sc, dc) SC4(sd, dd)
        }
        for (int q = qb + tid; q < q1; q += T_HIST) {
            int4 sa = sq[q];
            int4 da = dq[q];
            SC4(sa, da)
        }
#undef SC4
    }
    __syncthreads();
    // streaming flush: full partition range, float4, no atomics
    {
        float4* dst = (float4*)(partial + (size_t)slice * NTOT + base);
        const float4* src = (const float4*)hist;
        for (int i = tid; i < PART / 4; i += T_HIST) dst[i] = src[i];
    }
}

// ---- K4: finalize: out = dinv*(gs + sum_s partial[s][n]) + const ----
__global__ void finalize_kernel(const float* __restrict__ dinv, const float* __restrict__ gs,
                                const float* __restrict__ partial,
                                const float* __restrict__ gcn_b, const float* __restrict__ wb,
                                const float* __restrict__ bb, float* __restrict__ out) {
    __shared__ float scc;
    if (threadIdx.x < 32) {
        float pv = wb[threadIdx.x] * gcn_b[threadIdx.x];
        for (int off = 16; off; off >>= 1) pv += __shfl_down(pv, off, 32);
        if (threadIdx.x == 0) scc = pv + bb[0];
    }
    __syncthreads();
    int n = blockIdx.x * blockDim.x + threadIdx.x;
    if (n < N_NODES) {
        const float* ps = partial + n;
        float a0 = 0.f, a1 = 0.f, a2 = 0.f, a3 = 0.f;
#pragma unroll
        for (int s = 0; s < SLICES; s += 4) {
            a0 += ps[(size_t)(s + 0) * NTOT];
            a1 += ps[(size_t)(s + 1) * NTOT];
            a2 += ps[(size_t)(s + 2) * NTOT];
            a3 += ps[(size_t)(s + 3) * NTOT];
        }
        float agg = gs[n] + (a0 + a1) + (a2 + a3);   // gs = self-loop seed
        out[n] = dinv[n] * agg + scc;
    }
}

extern "C" void kernel_launch(void* const* d_in, const int* in_sizes, int n_in,
                              void* d_out, int out_size, void* d_ws, size_t ws_size,
                              hipStream_t stream) {
    const float* x       = (const float*)d_in[0];
    const void*  ei      = d_in[1];
    const float* w1      = (const float*)d_in[2];
    const float* b1      = (const float*)d_in[3];
    const float* bn_g    = (const float*)d_in[4];
    const float* bn_b    = (const float*)d_in[5];
    const float* prelu_a = (const float*)d_in[6];
    const float* w2      = (const float*)d_in[7];
    const float* b2      = (const float*)d_in[8];
    const float* gcn_w   = (const float*)d_in[9];
    const float* gcn_b   = (const float*)d_in[10];
    const float* wb      = (const float*)d_in[11];
    const float* bb      = (const float*)d_in[12];
    float* out = (float*)d_out;

    char* base = (char*)d_ws;
    double*        stats    = (double*)(base + OFF_STATS);
    float*         dinv     = (float*)(base + OFF_DINV);
    float*         gs       = (float*)(base + OFF_GS);
    unsigned char* partial8 = (unsigned char*)(base + OFF_PARTIAL);
    float*         partial  = (float*)(base + OFF_PARTIAL);   // reused after encoder reads u8

    // zero stats only (partials fully overwritten each pass)
    hipMemsetAsync(d_ws, 0, 1024, stream);

    stats_deg_kernel<<<DSLICES, T_HIST, 0, stream>>>(x, ei, stats, partial8);
    encoder_kernel<<<(N_NODES + 255) / 256, 256, 0, stream>>>(
        x, stats, w1, b1, bn_g, bn_b, prelu_a, w2, b2, gcn_w, wb, partial8, dinv, gs);
    scatter_kernel<<<BLOCKS_H, T_HIST, 0, stream>>>(ei, gs, partial);
    finalize_kernel<<<(N_NODES + 255) / 256, 256, 0, stream>>>(
        dinv, gs, partial, gcn_b, wb, bb, out);
}